// Round 1
// baseline (1823.267 us; speedup 1.0000x reference)
//
#include <hip/hip_runtime.h>
#include <math.h>

#define NPIX  25600      // 160*160
#define NANCH 76800      // 3*NPIX

// output layout (float elements)
constexpr int OUT_ANCH = 0;        // 76800*4
constexpr int OUT_OBJ  = 307200;   // 76800
constexpr int OUT_DELT = 384000;   // 76800*4
constexpr int OUT_FL   = 691200;   // 1000
constexpr int OUT_FB   = 692200;   // 1000*4

// workspace layout (bytes)
constexpr size_t Y_OFF      = 0;                        // 26,214,400 (f32)
constexpr size_t PROPS_OFF  = 26214400;                 // 76800*4*8
constexpr size_t KEYF_OFF   = PROPS_OFF + 2457600;      // 76800*4
constexpr size_t CANDK_OFF  = KEYF_OFF + 307200;        // 4096*4
constexpr size_t CANDI_OFF  = CANDK_OFF + 16384;        // 4096*4
constexpr size_t TSC_OFF    = CANDI_OFF + 16384;        // 2000*4 -> 8192
constexpr size_t TBOX_OFF   = TSC_OFF + 8192;           // 2000*4*8 -> 65536
constexpr size_t HIST_OFF   = TBOX_OFF + 65536;         // 256*4 -> 1024
constexpr size_t STATE_OFF  = HIST_OFF + 1024;          // -> 256
constexpr size_t MASK32_OFF = STATE_OFF + 256;          // 2000*64*4 = 512000

struct SelState { unsigned prefix; int remaining; int cntHi; int cntEq; };

__device__ __forceinline__ unsigned orderKey32(float f) {
  unsigned u = __float_as_uint(f);
  return (u & 0x80000000u) ? ~u : (u | 0x80000000u);
}
__device__ __forceinline__ float key32ToFloat(unsigned k) {
  unsigned u = (k & 0x80000000u) ? (k & 0x7fffffffu) : ~k;
  return __uint_as_float(u);
}

// ---------------------------------------------------------------- init
__global__ __launch_bounds__(256) void init_misc(float* __restrict__ out,
                                                 unsigned* __restrict__ hist,
                                                 SelState* __restrict__ st) {
  int t = blockIdx.x * 256 + threadIdx.x;
  if (t < 1000) out[OUT_FL + t] = -1e9f;
  if (t < 4000) out[OUT_FB + t] = 0.f;
  if (t < 256) hist[t] = 0u;
  if (t == 0) { st->prefix = 0u; st->remaining = 2000; st->cntHi = 0; st->cntEq = 0; }
}

// ---------------------------------------------------------------- LDS-tiled conv + bn + relu
// NUMERICS FROZEN (R9/R10/R11 pass): per-output fmaf chain ic 255->0, taps 8->0.
// V2: weights staged in LDS (broadcast ds_reads, no scalar-load stalls),
//     2 pixels/thread (16x32 tile) to amortize weight reads, input stride 35
//     (bank pattern 3y+2tx -> 2 lanes/bank = free).
__global__ __launch_bounds__(256) void conv_tiled_f32r(
    const float* __restrict__ x, const float* __restrict__ w,
    const float* __restrict__ bv, const float* __restrict__ gamma,
    const float* __restrict__ beta, const float* __restrict__ mean,
    const float* __restrict__ var, float* __restrict__ y) {
  const int tile = blockIdx.x;                 // 50 tiles: 10 rows x 5 cols
  const int th0 = (tile / 5) * 16;
  const int tw0 = (tile - (tile / 5) * 5) * 32;
  const int ob  = blockIdx.y * 16;
  const int tid = threadIdx.x;
  const int tx = tid & 15, ty = tid >> 4;
  const int x0 = tx * 2;                       // 2 pixels/thread (cols x0, x0+1)

  __shared__ float lin[8][18][35];             // 5040 floats; halo 18x34, stride 35
  __shared__ float lw[8][16][12];              // 1536 floats; rows 12-padded (16B aligned)

  float sreg[20];
  auto loadIn = [&](int cb) {
#pragma unroll
    for (int k = 0; k < 20; ++k) {
      int idx = tid + k * 256;
      float v = 0.f;
      if (idx < 5040) {
        int ci = idx / 630; int rem = idx - ci * 630;
        int r = rem / 35;   int c = rem - r * 35;
        int gh = th0 + r - 1, gw = tw0 + c - 1;
        if (c < 34 && (unsigned)gh < 160u && (unsigned)gw < 160u)
          v = x[(size_t)(cb + ci) * NPIX + gh * 160 + gw];
      }
      sreg[k] = v;
    }
  };
  float wreg[6];
  auto loadW = [&](int cb) {
#pragma unroll
    for (int k = 0; k < 6; ++k) {
      int idx = tid + k * 256;                 // 6*256 == 1536 exactly
      int ci = idx / 192; int rem = idx - ci * 192;
      int o = rem / 12;   int j = rem - o * 12;
      float v = 0.f;
      if (j < 9)
        v = w[(size_t)(ob + o) * 2304 + (size_t)(cb + ci) * 9 + j];
      wreg[k] = v;
    }
  };
  auto writeStage = [&]() {
#pragma unroll
    for (int k = 0; k < 20; ++k) {
      int idx = tid + k * 256;
      if (idx < 5040) ((float*)lin)[idx] = sreg[k];
    }
#pragma unroll
    for (int k = 0; k < 6; ++k)
      ((float*)lw)[tid + k * 256] = wreg[k];
  };

  float a0[16], a1[16];
#pragma unroll
  for (int i = 0; i < 16; ++i) { a0[i] = 0.f; a1[i] = 0.f; }

  loadIn(248); loadW(248);
  for (int cb = 248; cb >= 0; cb -= 8) {       // ic blocks DESCENDING
    __syncthreads();
    writeStage();
    __syncthreads();
    if (cb > 0) { loadIn(cb - 8); loadW(cb - 8); }   // prefetch next chunk
#pragma unroll
    for (int ci = 7; ci >= 0; --ci) {          // ic DESCENDING within block
      float i00 = lin[ci][ty    ][x0    ], i01 = lin[ci][ty    ][x0 + 1];
      float i02 = lin[ci][ty    ][x0 + 2], i03 = lin[ci][ty    ][x0 + 3];
      float i10 = lin[ci][ty + 1][x0    ], i11 = lin[ci][ty + 1][x0 + 1];
      float i12 = lin[ci][ty + 1][x0 + 2], i13 = lin[ci][ty + 1][x0 + 3];
      float i20 = lin[ci][ty + 2][x0    ], i21 = lin[ci][ty + 2][x0 + 1];
      float i22 = lin[ci][ty + 2][x0 + 2], i23 = lin[ci][ty + 2][x0 + 3];
      const float* wp = &lw[ci][0][0];
#pragma unroll
      for (int o = 0; o < 16; ++o) {
        const float4 wa = *(const float4*)(wp + o * 12);       // w0..w3 (16B aligned)
        const float4 wb = *(const float4*)(wp + o * 12 + 4);   // w4..w7
        const float w8v = wp[o * 12 + 8];
        // pixel 0 — taps 8->0, identical chain to frozen version
        float a = a0[o];
        a = fmaf(i22, w8v,  a); a = fmaf(i21, wb.w, a); a = fmaf(i20, wb.z, a);
        a = fmaf(i12, wb.y, a); a = fmaf(i11, wb.x, a); a = fmaf(i10, wa.w, a);
        a = fmaf(i02, wa.z, a); a = fmaf(i01, wa.y, a); a = fmaf(i00, wa.x, a);
        a0[o] = a;
        // pixel 1 — same chain shifted one column
        float b = a1[o];
        b = fmaf(i23, w8v,  b); b = fmaf(i22, wb.w, b); b = fmaf(i21, wb.z, b);
        b = fmaf(i13, wb.y, b); b = fmaf(i12, wb.x, b); b = fmaf(i11, wa.w, b);
        b = fmaf(i03, wa.z, b); b = fmaf(i02, wa.y, b); b = fmaf(i01, wa.x, b);
        a1[o] = b;
      }
    }
  }
  const int h = th0 + ty, wcol = tw0 + x0;
#pragma unroll
  for (int o = 0; o < 16; ++o) {
    int oc = ob + o;
    float sc = gamma[oc] / sqrtf(var[oc] + 1e-5f);
    float sh = (bv[oc] - mean[oc]) * sc + beta[oc];
    float v0 = fmaf(a0[o], sc, sh);
    float v1 = fmaf(a1[o], sc, sh);
    v0 = (v0 > 0.f) ? v0 : 0.f;
    v1 = (v1 > 0.f) ? v1 : 0.f;
    float2 vv; vv.x = v0; vv.y = v1;
    *(float2*)&y[(size_t)oc * NPIX + h * 160 + wcol] = vv;   // wcol even -> 8B aligned
  }
}

// ---------------------------------------------------------------- heads (f32, reversed c) + anchors + proposals (FROZEN)
__global__ __launch_bounds__(256) void heads_kernel(
    const float* __restrict__ y,
    const float* __restrict__ det_w, const float* __restrict__ det_b,
    const float* __restrict__ reg_w, const float* __restrict__ reg_b,
    float* __restrict__ out, double* __restrict__ props,
    float* __restrict__ keyf) {
  const int p = blockIdx.x * 256 + threadIdx.x;
  float od0 = 0.f, od1 = 0.f, od2 = 0.f;
  float rg[12];
#pragma unroll
  for (int o = 0; o < 12; ++o) rg[o] = 0.f;
  const float* yp = y + p;
  for (int c = 255; c >= 0; --c) {      // reversed accumulation
    float v = yp[(size_t)c * NPIX];
    od0 = fmaf(v, det_w[c], od0);
    od1 = fmaf(v, det_w[256 + c], od1);
    od2 = fmaf(v, det_w[512 + c], od2);
#pragma unroll
    for (int o = 0; o < 12; ++o) rg[o] = fmaf(v, reg_w[o * 256 + c], rg[o]);
  }
  const int hh = p / 160;
  const int ww = p - hh * 160;
  const float sx = ww * 4.0f, sy = hh * 4.0f;
  float odv[3] = {od0, od1, od2};
#pragma unroll
  for (int a = 0; a < 3; ++a) {
    float ar = (a == 0) ? 0.5f : ((a == 1) ? 1.0f : 2.0f);
    float sq = sqrtf(ar);
    float haf = 64.0f * sq, waf = 64.0f / sq;
    float ax1 = fminf(fmaxf(sx - waf * 0.5f, 0.f), 640.f);
    float ay1 = fminf(fmaxf(sy - haf * 0.5f, 0.f), 640.f);
    float ax2 = fminf(fmaxf(sx + waf * 0.5f, 0.f), 640.f);
    float ay2 = fminf(fmaxf(sy + haf * 0.5f, 0.f), 640.f);
    int ai = a * NPIX + p;
    out[OUT_ANCH + ai * 4 + 0] = ax1;
    out[OUT_ANCH + ai * 4 + 1] = ay1;
    out[OUT_ANCH + ai * 4 + 2] = ax2;
    out[OUT_ANCH + ai * 4 + 3] = ay2;
    float logit = odv[a] + det_b[a];
    out[OUT_OBJ + ai] = logit;
    float dx = rg[0 + a] + reg_b[0 + a];
    float dy = rg[3 + a] + reg_b[3 + a];
    float dw = rg[6 + a] + reg_b[6 + a];
    float dh = rg[9 + a] + reg_b[9 + a];
    out[OUT_DELT + ai * 4 + 0] = dx;
    out[OUT_DELT + ai * 4 + 1] = dy;
    out[OUT_DELT + ai * 4 + 2] = dw;
    out[OUT_DELT + ai * 4 + 3] = dh;
    float aw = ax2 - ax1, ah = ay2 - ay1;
    float cx = ax1 + 0.5f * aw, cy = ay1 + 0.5f * ah;
    float pcx = dx * aw + cx, pcy = dy * ah + cy;
    float pw = aw * expf(dw), ph = ah * expf(dh);
    props[ai * 4 + 0] = (double)fminf(fmaxf(pcx - 0.5f * pw, 0.f), 640.f);
    props[ai * 4 + 1] = (double)fminf(fmaxf(pcy - 0.5f * ph, 0.f), 640.f);
    props[ai * 4 + 2] = (double)fminf(fmaxf(pcx + 0.5f * pw, 0.f), 640.f);
    props[ai * 4 + 3] = (double)fminf(fmaxf(pcy + 0.5f * ph, 0.f), 640.f);
    keyf[ai] = (logit > 0.f) ? logit : -1e9f;   // sigmoid>0.5 <=> logit>0
  }
}

// ---------------------------------------------------------------- radix select (R11-proven)
__global__ __launch_bounds__(256) void hist_pass(const float* __restrict__ keyf,
                                                 unsigned* __restrict__ hist,
                                                 const SelState* __restrict__ st, int pass) {
  __shared__ unsigned lh[256];
  lh[threadIdx.x] = 0u;
  __syncthreads();
  unsigned prefix = st->prefix;
  int shift = 24 - 8 * pass;
  int i = blockIdx.x * 256 + threadIdx.x;   // 300*256 = 76800 exactly
  unsigned k = orderKey32(keyf[i]);
  bool ok = (pass == 0) || ((k >> (shift + 8)) == prefix);
  if (ok) atomicAdd(&lh[(k >> shift) & 255u], 1u);
  __syncthreads();
  unsigned c = lh[threadIdx.x];
  if (c) atomicAdd(&hist[threadIdx.x], c);
}

__global__ void pick_kernel(unsigned* __restrict__ hist, SelState* __restrict__ st) {
  if (threadIdx.x == 0 && blockIdx.x == 0) {
    int rem = st->remaining;
    unsigned cum = 0;
    int b = 0;
    for (int i = 255; i >= 0; --i) {
      unsigned h = hist[i];
      if (cum + h >= (unsigned)rem) { b = i; break; }
      cum += h;
    }
    st->prefix = (st->prefix << 8) | (unsigned)b;
    st->remaining = rem - (int)cum;
    for (int i = 0; i < 256; ++i) hist[i] = 0u;
  }
}

__global__ __launch_bounds__(256) void compact_kernel(const float* __restrict__ keyf,
                                                      SelState* __restrict__ st,
                                                      unsigned* __restrict__ candk,
                                                      unsigned* __restrict__ candi) {
  int i = blockIdx.x * 256 + threadIdx.x;
  if (i >= NANCH) return;
  unsigned k = orderKey32(keyf[i]);
  unsigned T = st->prefix;
  if (k > T) {
    int pos = atomicAdd(&st->cntHi, 1);
    if (pos < 2048) { candk[pos] = k; candi[pos] = (unsigned)i; }
  } else if (k == T) {
    int pos = atomicAdd(&st->cntEq, 1);
    if (pos < 2048) { candk[2048 + pos] = k; candi[2048 + pos] = (unsigned)i; }
  }
}

__global__ __launch_bounds__(1024) void sort_gather(const unsigned* __restrict__ candk,
                                                    const unsigned* __restrict__ candi,
                                                    const SelState* __restrict__ st,
                                                    const double* __restrict__ props,
                                                    float* __restrict__ tsc,
                                                    double* __restrict__ tbox) {
  __shared__ unsigned ka[4096];
  __shared__ unsigned ia[4096];
  int nHi = st->cntHi; if (nHi > 2048) nHi = 2048;
  int nEq = st->cntEq; if (nEq > 2048) nEq = 2048;
  for (int i = threadIdx.x; i < 4096; i += 1024) {
    bool real = (i < nHi) || (i >= 2048 && i < 2048 + nEq);
    ka[i] = real ? candk[i] : 0u;
    ia[i] = real ? candi[i] : 0xffffffffu;
  }
  __syncthreads();
  for (int k = 2; k <= 4096; k <<= 1) {
    for (int j = k >> 1; j > 0; j >>= 1) {
      for (int e = threadIdx.x; e < 4096; e += 1024) {
        int l = e ^ j;
        if (l > e) {
          unsigned ke = ka[e], kl = ka[l];
          unsigned ie = ia[e], il = ia[l];
          bool descending = ((e & k) == 0);
          bool lBetter = (kl > ke) || (kl == ke && il < ie);
          bool eBetter = (ke > kl) || (ke == kl && ie < il);
          bool sw = descending ? lBetter : eBetter;
          if (sw) { ka[e] = kl; ka[l] = ke; ia[e] = il; ia[l] = ie; }
        }
      }
      __syncthreads();
    }
  }
  for (int t = threadIdx.x; t < 2000; t += 1024) {
    unsigned idx = ia[t];
    if (idx < (unsigned)NANCH) {
      tsc[t] = key32ToFloat(ka[t]);
      tbox[t * 4 + 0] = props[(size_t)idx * 4 + 0];
      tbox[t * 4 + 1] = props[(size_t)idx * 4 + 1];
      tbox[t * 4 + 2] = props[(size_t)idx * 4 + 2];
      tbox[t * 4 + 3] = props[(size_t)idx * 4 + 3];
    } else {
      tsc[t] = -1e9f;     // invalid: never kept, never output
      tbox[t * 4 + 0] = 0.0; tbox[t * 4 + 1] = 0.0;
      tbox[t * 4 + 2] = 0.0; tbox[t * 4 + 3] = 0.0;
    }
  }
}

// ---------------------------------------------------------------- IoU bitmask (parallel; f64 formula verbatim from R11 NMS)
// word layout: mask32[i*64 + l] covers j in [l*32, l*32+32); bits only for j>i.
__global__ __launch_bounds__(256) void iou_mask(const double* __restrict__ tbox,
                                                unsigned* __restrict__ mask32) {
  int gid = blockIdx.x * 256 + threadIdx.x;
  if (gid >= 2000 * 64) return;
  int i = gid >> 6, l = gid & 63;
  int j0 = l * 32;
  unsigned m = 0u;
  if (j0 + 31 > i) {                       // word contains some j>i
    double bix = tbox[i * 4 + 0], biy = tbox[i * 4 + 1];
    double biz = tbox[i * 4 + 2], biw = tbox[i * 4 + 3];
    double areai = (biz - bix) * (biw - biy);
#pragma unroll 4
    for (int b = 0; b < 32; ++b) {
      int j = j0 + b;
      if (j >= 2000 || j <= i) continue;
      double bjx = tbox[j * 4 + 0], bjy = tbox[j * 4 + 1];
      double bjz = tbox[j * 4 + 2], bjw = tbox[j * 4 + 3];
      double xx1 = fmax(bix, bjx), yy1 = fmax(biy, bjy);
      double xx2 = fmin(biz, bjz), yy2 = fmin(biw, bjw);
      double iw = fmax(xx2 - xx1, 0.0), ih = fmax(yy2 - yy1, 0.0);
      double inter = iw * ih;
      double areaj = (bjz - bjx) * (bjw - bjy);
      double iou = inter / (areai + areaj - inter + 1e-9);
      if (iou > 0.7) m |= (1u << b);
    }
  }
  mask32[(size_t)i * 64 + l] = m;
}

// ---------------------------------------------------------------- greedy scan: single wave, zero barriers
// Equivalent to the validated fori_loop: keep[j] cleared iff some kept i<j has
// iou>0.7 (bits precomputed). Lockstep wave; LDS ops in program order.
__global__ __launch_bounds__(64) void nms_scan(const unsigned* __restrict__ mask32,
                                               const float* __restrict__ tsc,
                                               const double* __restrict__ tbox,
                                               float* __restrict__ out) {
  __shared__ unsigned kw[64];        // keep bitmask, u32 word per lane
  __shared__ unsigned wpfx[65];
  const int lane = threadIdx.x;
  kw[lane] = 0u;
  for (int i = lane; i < 2000; i += 64)
    if (tsc[i] > -5e8f) atomicOr(&kw[i >> 5], 1u << (i & 31));   // valid bits

  constexpr int PF = 8;
  unsigned mrow[PF];
#pragma unroll
  for (int q = 0; q < PF; ++q) mrow[q] = mask32[(size_t)q * 64 + lane];

  unsigned curw = kw[0];
  int curwi = 0;
  for (int i0 = 0; i0 < 2000; i0 += PF) {      // 2000 % 8 == 0
#pragma unroll
    for (int q = 0; q < PF; ++q) {
      int i = i0 + q;
      int wi = i >> 5;
      if (wi != curwi) { curw = kw[wi]; curwi = wi; }
      unsigned m = mrow[q];
      int ni = i + PF;
      if (ni < 2000) mrow[q] = mask32[(size_t)ni * 64 + lane];   // prefetch
      if ((curw >> (i & 31)) & 1u) {           // kept (uniform branch)
        kw[lane] &= ~m;                        // clear suppressed j's
        curw = kw[curwi];                      // re-sync cached word
      }
    }
  }

  if (lane == 0) {
    wpfx[0] = 0;
    for (int w = 0; w < 64; ++w) wpfx[w + 1] = wpfx[w] + __popc(kw[w]);
  }
  // single wave: lane0's writes ordered before subsequent reads
  for (int i = lane; i < 2000; i += 64) {
    if ((kw[i >> 5] >> (i & 31)) & 1u) {
      int r = (int)wpfx[i >> 5] + __popc(kw[i >> 5] & ((1u << (i & 31)) - 1u));
      if (r < 1000) {
        out[OUT_FL + r] = tsc[i];
        out[OUT_FB + r * 4 + 0] = (float)tbox[i * 4 + 0];
        out[OUT_FB + r * 4 + 1] = (float)tbox[i * 4 + 1];
        out[OUT_FB + r * 4 + 2] = (float)tbox[i * 4 + 2];
        out[OUT_FB + r * 4 + 3] = (float)tbox[i * 4 + 3];
      }
    }
  }
}

// ---------------------------------------------------------------- launch
extern "C" void kernel_launch(void* const* d_in, const int* in_sizes, int n_in,
                              void* d_out, int out_size, void* d_ws, size_t ws_size,
                              hipStream_t stream) {
  (void)in_sizes; (void)n_in; (void)out_size; (void)ws_size;
  const float* x      = (const float*)d_in[0];
  const float* conv_w = (const float*)d_in[1];
  const float* conv_b = (const float*)d_in[2];
  const float* gamma  = (const float*)d_in[3];
  const float* beta   = (const float*)d_in[4];
  const float* mean   = (const float*)d_in[5];
  const float* var    = (const float*)d_in[6];
  const float* det_w  = (const float*)d_in[7];
  const float* det_b  = (const float*)d_in[8];
  const float* reg_w  = (const float*)d_in[9];
  const float* reg_b  = (const float*)d_in[10];
  float* out = (float*)d_out;
  char* ws = (char*)d_ws;

  float*  y      = (float*)(ws + Y_OFF);
  double* props  = (double*)(ws + PROPS_OFF);
  float*  keyf   = (float*)(ws + KEYF_OFF);
  unsigned* candk = (unsigned*)(ws + CANDK_OFF);
  unsigned* candi = (unsigned*)(ws + CANDI_OFF);
  float*  tsc    = (float*)(ws + TSC_OFF);
  double* tbox   = (double*)(ws + TBOX_OFF);
  unsigned* hist = (unsigned*)(ws + HIST_OFF);
  SelState* st   = (SelState*)(ws + STATE_OFF);
  unsigned* mask32 = (unsigned*)(ws + MASK32_OFF);

  init_misc<<<16, 256, 0, stream>>>(out, hist, st);
  conv_tiled_f32r<<<dim3(50, 16), 256, 0, stream>>>(x, conv_w, conv_b, gamma, beta, mean, var, y);
  heads_kernel<<<100, 256, 0, stream>>>(y, det_w, det_b, reg_w, reg_b, out, props, keyf);
  for (int p = 0; p < 4; ++p) {
    hist_pass<<<300, 256, 0, stream>>>(keyf, hist, st, p);
    pick_kernel<<<1, 64, 0, stream>>>(hist, st);
  }
  compact_kernel<<<300, 256, 0, stream>>>(keyf, st, candk, candi);
  sort_gather<<<1, 1024, 0, stream>>>(candk, candi, st, props, tsc, tbox);
  iou_mask<<<500, 256, 0, stream>>>(tbox, mask32);
  nms_scan<<<1, 64, 0, stream>>>(mask32, tsc, tbox, out);
}